// Round 1
// baseline (288.894 us; speedup 1.0000x reference)
//
#include <hip/hip_runtime.h>

// Problem constants
#define BB 4
#define SS 2048
#define EE 640
#define NHH 10
#define DHH 64
#define MTOK 8192   // BB*SS
#define E33 1920

#define LDST 72     // LDS row stride (elements): 144B, 16B-aligned, bank-spreading

typedef float f32x4 __attribute__((ext_vector_type(4)));
typedef __bf16 bf16x8 __attribute__((ext_vector_type(8)));
typedef unsigned short u16;
typedef u16 u16x4 __attribute__((ext_vector_type(4)));

__device__ inline u16 f2bf(float f) {
  unsigned u = __builtin_bit_cast(unsigned, f);
  u += 0x7fffu + ((u >> 16) & 1u);   // round-to-nearest-even
  return (u16)(u >> 16);
}

// ---------------------------------------------------------------- convert
__global__ void convert_kernel(const float* __restrict__ in, u16* __restrict__ out, int n4) {
  int i = blockIdx.x * blockDim.x + threadIdx.x;
  if (i < n4) {
    float4 v = ((const float4*)in)[i];
    u16x4 o = { f2bf(v.x), f2bf(v.y), f2bf(v.z), f2bf(v.w) };
    ((u16x4*)out)[i] = o;
  }
}

// ---------------------------------------------------------------- QKV GEMM
// C[8192,1920] = A[8192,640] * Bt[1920,640]^T, scatter into q/k/v^T buffers.
__global__ __launch_bounds__(256) void gemm_qkv(
    const u16* __restrict__ A, const u16* __restrict__ Bt,
    u16* __restrict__ qb, u16* __restrict__ kb, u16* __restrict__ vt) {
  __shared__ __align__(16) u16 As[128 * LDST];
  __shared__ __align__(16) u16 Bs[128 * LDST];
  const int t = threadIdx.x;
  const int m0 = blockIdx.y * 128;
  const int n0 = blockIdx.x * 128;
  const int w = t >> 6, lane = t & 63, n16 = lane & 15, quad = lane >> 4;
  const int wm = w >> 1, wn = w & 1;

  f32x4 acc[4][4];
  for (int i = 0; i < 4; i++)
    for (int j = 0; j < 4; j++) acc[i][j] = f32x4{0.f, 0.f, 0.f, 0.f};

  for (int kt = 0; kt < 10; ++kt) {       // K=640, BK=64
    __syncthreads();
    for (int i = 0; i < 4; ++i) {
      int c = i * 256 + t;
      int row = c >> 3, col0 = (c & 7) * 8;
      *(bf16x8*)&As[row * LDST + col0] = *(const bf16x8*)&A[(m0 + row) * 640 + kt * 64 + col0];
      *(bf16x8*)&Bs[row * LDST + col0] = *(const bf16x8*)&Bt[(n0 + row) * 640 + kt * 64 + col0];
    }
    __syncthreads();
    for (int ks = 0; ks < 2; ++ks) {
      bf16x8 a[4], b[4];
      for (int mi = 0; mi < 4; mi++)
        a[mi] = *(const bf16x8*)&As[(wm * 64 + mi * 16 + n16) * LDST + ks * 32 + quad * 8];
      for (int ni = 0; ni < 4; ni++)
        b[ni] = *(const bf16x8*)&Bs[(wn * 64 + ni * 16 + n16) * LDST + ks * 32 + quad * 8];
      for (int mi = 0; mi < 4; mi++)
        for (int ni = 0; ni < 4; ni++)
          acc[mi][ni] = __builtin_amdgcn_mfma_f32_16x16x32_bf16(a[mi], b[ni], acc[mi][ni], 0, 0, 0);
    }
  }

  // Epilogue: col e -> which = e/640 (uniform per block since 640 % 128 == 0)
  const int which = n0 / 640;
  for (int ni = 0; ni < 4; ni++) {
    int col = n0 + wn * 64 + ni * 16 + n16;
    int eh = col - which * 640;
    int h = eh >> 6, d = eh & 63;
    for (int mi = 0; mi < 4; mi++) {
      int tb = m0 + wm * 64 + mi * 16 + quad * 4;   // 4 consecutive tokens (r=0..3)
      f32x4 c = acc[mi][ni];
      if (which == 2) {
        // v^T[bh][d][s], 4 consecutive s -> packed 8B store
        int b_ = tb >> 11, s_ = tb & 2047;
        u16x4 pk = { f2bf(c[0]), f2bf(c[1]), f2bf(c[2]), f2bf(c[3]) };
        *(u16x4*)&vt[((b_ * NHH + h) * DHH + d) * SS + s_] = pk;
      } else {
        u16* dst = (which == 0) ? qb : kb;
        for (int r = 0; r < 4; r++) {
          int tok = tb + r;
          int b_ = tok >> 11, s_ = tok & 2047;
          dst[((b_ * NHH + h) * SS + s_) * DHH + d] = f2bf(c[r]);
        }
      }
    }
  }
}

// ---------------------------------------------------------------- attention
// One block: 64 q rows of one (b,h); 4 waves x 16 q rows. Online softmax in regs.
__global__ __launch_bounds__(256) void attn_kernel(
    const u16* __restrict__ qb, const u16* __restrict__ kb, const u16* __restrict__ vt,
    u16* __restrict__ y) {
  __shared__ __align__(16) u16 Ks[64 * LDST];       // K[key][d]
  __shared__ __align__(16) u16 Vs[64 * LDST];       // V^T[d][key]
  __shared__ __align__(16) u16 Ps[4 * 16 * LDST];   // per-wave P[q][key]
  const int t = threadIdx.x;
  const int w = t >> 6, lane = t & 63, n16 = lane & 15, quad = lane >> 4;
  const int bh = blockIdx.y, qt = blockIdx.x;
  const int qb0 = qt * 64;
  const int b_ = bh / NHH, h = bh % NHH;

  // Q A-fragments: A[m=lane&15 -> q row][k=d=quad*8+j], 2 k-steps of 32
  bf16x8 aq[2];
  {
    const u16* qp = &qb[(bh * SS + qb0 + w * 16 + n16) * DHH];
    aq[0] = *(const bf16x8*)&qp[quad * 8];
    aq[1] = *(const bf16x8*)&qp[32 + quad * 8];
  }

  float m_i[4], l_i[4];
  f32x4 o[4];
  for (int r = 0; r < 4; r++) { m_i[r] = -1e30f; l_i[r] = 0.f; }
  for (int nb = 0; nb < 4; nb++) o[nb] = f32x4{0.f, 0.f, 0.f, 0.f};

  for (int kt = 0; kt <= qt; ++kt) {
    __syncthreads();
    for (int i = 0; i < 2; ++i) {
      int c = i * 256 + t;
      int row = c >> 3, col0 = (c & 7) * 8;
      *(bf16x8*)&Ks[row * LDST + col0] = *(const bf16x8*)&kb[(bh * SS + kt * 64 + row) * DHH + col0];
      *(bf16x8*)&Vs[row * LDST + col0] = *(const bf16x8*)&vt[(bh * DHH + row) * SS + kt * 64 + col0];
    }
    __syncthreads();

    // scores: 4 key-blocks of 16
    f32x4 sc[4];
    for (int nb = 0; nb < 4; nb++) {
      f32x4 c = f32x4{0.f, 0.f, 0.f, 0.f};
      for (int ks = 0; ks < 2; ks++) {
        bf16x8 bk = *(const bf16x8*)&Ks[(nb * 16 + n16) * LDST + ks * 32 + quad * 8];
        c = __builtin_amdgcn_mfma_f32_16x16x32_bf16(aq[ks], bk, c, 0, 0, 0);
      }
      for (int r = 0; r < 4; r++) c[r] *= 0.125f;
      sc[nb] = c;
    }
    if (kt == qt) {  // diagonal tile causal mask: key_rel > q_rel
      for (int nb = 0; nb < 4; nb++)
        for (int r = 0; r < 4; r++)
          if (nb * 16 + n16 > w * 16 + quad * 4 + r) sc[nb][r] = -1e30f;
    }

    // online softmax; row r of this lane = quad*4+r, stats replicated over 16 lanes/quad
    float p[4][4];
    for (int r = 0; r < 4; r++) {
      float rm = fmaxf(fmaxf(sc[0][r], sc[1][r]), fmaxf(sc[2][r], sc[3][r]));
      for (int off = 1; off < 16; off <<= 1) rm = fmaxf(rm, __shfl_xor(rm, off));
      float mnew = fmaxf(m_i[r], rm);
      float alpha = __expf(m_i[r] - mnew);
      float rs = 0.f;
      for (int nb = 0; nb < 4; nb++) { float pv = __expf(sc[nb][r] - mnew); p[nb][r] = pv; rs += pv; }
      for (int off = 1; off < 16; off <<= 1) rs += __shfl_xor(rs, off);
      l_i[r] = l_i[r] * alpha + rs;
      m_i[r] = mnew;
      for (int nb = 0; nb < 4; nb++) o[nb][r] *= alpha;
    }

    // P: C-layout -> LDS -> A-layout (per-wave region)
    u16* Pw = &Ps[w * 16 * LDST];
    for (int nb = 0; nb < 4; nb++)
      for (int r = 0; r < 4; r++)
        Pw[(quad * 4 + r) * LDST + nb * 16 + n16] = f2bf(p[nb][r]);
    __syncthreads();

    bf16x8 ap[2];
    ap[0] = *(const bf16x8*)&Pw[n16 * LDST + quad * 8];
    ap[1] = *(const bf16x8*)&Pw[n16 * LDST + 32 + quad * 8];
    for (int nb = 0; nb < 4; nb++)
      for (int ks = 0; ks < 2; ks++) {
        bf16x8 bv = *(const bf16x8*)&Vs[(nb * 16 + n16) * LDST + ks * 32 + quad * 8];
        o[nb] = __builtin_amdgcn_mfma_f32_16x16x32_bf16(ap[ks], bv, o[nb], 0, 0, 0);
      }
  }

  // epilogue: y[token][h*64+d] bf16
  for (int r = 0; r < 4; r++) {
    int qrow = qb0 + w * 16 + quad * 4 + r;
    float inv = 1.0f / l_i[r];
    int tok = b_ * SS + qrow;
    for (int nb = 0; nb < 4; nb++)
      y[tok * EE + h * DHH + nb * 16 + n16] = f2bf(o[nb][r] * inv);
  }
}

// ---------------------------------------------------------------- proj GEMM
// out[8192,640] fp32 = y[8192,640] * wproj[640,640]^T
__global__ __launch_bounds__(256) void gemm_proj(
    const u16* __restrict__ A, const u16* __restrict__ Bt, float* __restrict__ out) {
  __shared__ __align__(16) u16 As[128 * LDST];
  __shared__ __align__(16) u16 Bs[128 * LDST];
  const int t = threadIdx.x;
  const int m0 = blockIdx.y * 128;
  const int n0 = blockIdx.x * 128;
  const int w = t >> 6, lane = t & 63, n16 = lane & 15, quad = lane >> 4;
  const int wm = w >> 1, wn = w & 1;

  f32x4 acc[4][4];
  for (int i = 0; i < 4; i++)
    for (int j = 0; j < 4; j++) acc[i][j] = f32x4{0.f, 0.f, 0.f, 0.f};

  for (int kt = 0; kt < 10; ++kt) {
    __syncthreads();
    for (int i = 0; i < 4; ++i) {
      int c = i * 256 + t;
      int row = c >> 3, col0 = (c & 7) * 8;
      *(bf16x8*)&As[row * LDST + col0] = *(const bf16x8*)&A[(m0 + row) * 640 + kt * 64 + col0];
      *(bf16x8*)&Bs[row * LDST + col0] = *(const bf16x8*)&Bt[(n0 + row) * 640 + kt * 64 + col0];
    }
    __syncthreads();
    for (int ks = 0; ks < 2; ++ks) {
      bf16x8 a[4], b[4];
      for (int mi = 0; mi < 4; mi++)
        a[mi] = *(const bf16x8*)&As[(wm * 64 + mi * 16 + n16) * LDST + ks * 32 + quad * 8];
      for (int ni = 0; ni < 4; ni++)
        b[ni] = *(const bf16x8*)&Bs[(wn * 64 + ni * 16 + n16) * LDST + ks * 32 + quad * 8];
      for (int mi = 0; mi < 4; mi++)
        for (int ni = 0; ni < 4; ni++)
          acc[mi][ni] = __builtin_amdgcn_mfma_f32_16x16x32_bf16(a[mi], b[ni], acc[mi][ni], 0, 0, 0);
    }
  }

  for (int ni = 0; ni < 4; ni++) {
    int col = n0 + wn * 64 + ni * 16 + n16;
    for (int mi = 0; mi < 4; mi++) {
      int rowb = m0 + wm * 64 + mi * 16 + quad * 4;
      f32x4 c = acc[mi][ni];
      for (int r = 0; r < 4; r++) out[(rowb + r) * 640 + col] = c[r];
    }
  }
}

// ---------------------------------------------------------------- launch
extern "C" void kernel_launch(void* const* d_in, const int* in_sizes, int n_in,
                              void* d_out, int out_size, void* d_ws, size_t ws_size,
                              hipStream_t stream) {
  const float* x     = (const float*)d_in[0];   // [4,2048,640]
  const float* wqkv  = (const float*)d_in[1];   // [1920,640]
  const float* wproj = (const float*)d_in[2];   // [640,640]
  float* out = (float*)d_out;

  char* ws = (char*)d_ws;
  u16* xb     = (u16*)(ws + 0);            // 10,485,760 B
  u16* wqkvb  = (u16*)(ws + 10485760);     //  2,457,600 B
  u16* wprojb = (u16*)(ws + 12943360);     //    819,200 B
  u16* qbuf   = (u16*)(ws + 13762560);     // 10,485,760 B  [bh][s][d]
  u16* kbuf   = (u16*)(ws + 24248320);     // 10,485,760 B  [bh][s][d]
  u16* vtb    = (u16*)(ws + 34734080);     // 10,485,760 B  [bh][d][s]
  u16* ybuf   = (u16*)(ws + 45219840);     // 10,485,760 B  [tok][e]

  convert_kernel<<<5120, 256, 0, stream>>>(x, xb, 5242880 / 4);
  convert_kernel<<<1200, 256, 0, stream>>>(wqkv, wqkvb, 1228800 / 4);
  convert_kernel<<<400, 256, 0, stream>>>(wproj, wprojb, 409600 / 4);

  gemm_qkv<<<dim3(15, 64), 256, 0, stream>>>(xb, wqkvb, qbuf, kbuf, vtb);
  attn_kernel<<<dim3(32, 40), 256, 0, stream>>>(qbuf, kbuf, vtb, ybuf);
  gemm_proj<<<dim3(5, 64), 256, 0, stream>>>(ybuf, wprojb, out);
}

// Round 2
// 183.508 us; speedup vs baseline: 1.5743x; 1.5743x over previous
//
#include <hip/hip_runtime.h>

// Problem constants
#define BB 4
#define SS 2048
#define EE 640
#define NHH 10
#define DHH 64
#define MTOK 8192   // BB*SS
#define E33 1920

#define LDST 72     // LDS row stride (elements): 144B, 16B-aligned, bank-spreading

typedef float f32x4 __attribute__((ext_vector_type(4)));
typedef __bf16 bf16x8 __attribute__((ext_vector_type(8)));
typedef unsigned short u16;
typedef u16 u16x4 __attribute__((ext_vector_type(4)));

__device__ inline u16 f2bf(float f) {
  unsigned u = __builtin_bit_cast(unsigned, f);
  u += 0x7fffu + ((u >> 16) & 1u);   // round-to-nearest-even
  return (u16)(u >> 16);
}

// ---------------------------------------------------------------- convert
__global__ void convert_kernel(const float* __restrict__ in, u16* __restrict__ out, int n4) {
  int i = blockIdx.x * blockDim.x + threadIdx.x;
  if (i < n4) {
    float4 v = ((const float4*)in)[i];
    u16x4 o = { f2bf(v.x), f2bf(v.y), f2bf(v.z), f2bf(v.w) };
    ((u16x4*)out)[i] = o;
  }
}

// ---------------------------------------------------------------- QKV GEMM
// C[8192,1920] = A[8192,640] * Bt[1920,640]^T, scatter into q/k/v^T buffers.
__global__ __launch_bounds__(256) void gemm_qkv(
    const u16* __restrict__ A, const u16* __restrict__ Bt,
    u16* __restrict__ qb, u16* __restrict__ kb, u16* __restrict__ vt) {
  __shared__ __align__(16) u16 As[128 * LDST];
  __shared__ __align__(16) u16 Bs[128 * LDST];
  const int t = threadIdx.x;
  const int m0 = blockIdx.y * 128;
  const int n0 = blockIdx.x * 128;
  const int w = t >> 6, lane = t & 63, n16 = lane & 15, quad = lane >> 4;
  const int wm = w >> 1, wn = w & 1;

  f32x4 acc[4][4];
  for (int i = 0; i < 4; i++)
    for (int j = 0; j < 4; j++) acc[i][j] = f32x4{0.f, 0.f, 0.f, 0.f};

  for (int kt = 0; kt < 10; ++kt) {       // K=640, BK=64
    __syncthreads();
    for (int i = 0; i < 4; ++i) {
      int c = i * 256 + t;
      int row = c >> 3, col0 = (c & 7) * 8;
      *(bf16x8*)&As[row * LDST + col0] = *(const bf16x8*)&A[(m0 + row) * 640 + kt * 64 + col0];
      *(bf16x8*)&Bs[row * LDST + col0] = *(const bf16x8*)&Bt[(n0 + row) * 640 + kt * 64 + col0];
    }
    __syncthreads();
    for (int ks = 0; ks < 2; ++ks) {
      bf16x8 a[4], b[4];
      for (int mi = 0; mi < 4; mi++)
        a[mi] = *(const bf16x8*)&As[(wm * 64 + mi * 16 + n16) * LDST + ks * 32 + quad * 8];
      for (int ni = 0; ni < 4; ni++)
        b[ni] = *(const bf16x8*)&Bs[(wn * 64 + ni * 16 + n16) * LDST + ks * 32 + quad * 8];
      for (int mi = 0; mi < 4; mi++)
        for (int ni = 0; ni < 4; ni++)
          acc[mi][ni] = __builtin_amdgcn_mfma_f32_16x16x32_bf16(a[mi], b[ni], acc[mi][ni], 0, 0, 0);
    }
  }

  // Epilogue: col e -> which = e/640 (uniform per block since 640 % 128 == 0)
  const int which = n0 / 640;
  for (int ni = 0; ni < 4; ni++) {
    int col = n0 + wn * 64 + ni * 16 + n16;
    int eh = col - which * 640;
    int h = eh >> 6, d = eh & 63;
    for (int mi = 0; mi < 4; mi++) {
      int tb = m0 + wm * 64 + mi * 16 + quad * 4;   // 4 consecutive tokens (r=0..3)
      f32x4 c = acc[mi][ni];
      if (which == 2) {
        // v^T[bh][d][s], 4 consecutive s -> packed 8B store
        int b_ = tb >> 11, s_ = tb & 2047;
        u16x4 pk = { f2bf(c[0]), f2bf(c[1]), f2bf(c[2]), f2bf(c[3]) };
        *(u16x4*)&vt[((b_ * NHH + h) * DHH + d) * SS + s_] = pk;
      } else {
        u16* dst = (which == 0) ? qb : kb;
        for (int r = 0; r < 4; r++) {
          int tok = tb + r;
          int b_ = tok >> 11, s_ = tok & 2047;
          dst[((b_ * NHH + h) * SS + s_) * DHH + d] = f2bf(c[r]);
        }
      }
    }
  }
}

// ---------------------------------------------------------------- attention
// One block: 64 q rows of one (b,h); 4 waves x 16 q rows.
// S^T = K*Q^T trick: scores come out with col=lane&15=q, so softmax stats are
// per-lane scalars (2 shfls) and P^T is directly the B-operand of O^T = V^T*P^T
// -- no P LDS round-trip, no 3rd barrier. K rows staged permuted so the lane's
// 16 score regs enumerate keys p*32+quad*8+j (the K=32 B-frag pattern).
__global__ __launch_bounds__(256) void attn_kernel(
    const u16* __restrict__ qb, const u16* __restrict__ kb, const u16* __restrict__ vt,
    u16* __restrict__ y) {
  __shared__ __align__(16) u16 Ks[2][64 * LDST];   // K[perm(key)][d], double-buffered
  __shared__ __align__(16) u16 Vs[2][64 * LDST];   // V^T[d][key]
  const int t = threadIdx.x;
  const int w = t >> 6, lane = t & 63, n16 = lane & 15, quad = lane >> 4;
  const int bh = blockIdx.x;
  const int qt = 31 - blockIdx.y;        // longest blocks first
  const int qb0 = qt * 64;
  const int b_ = bh / NHH, h = bh % NHH;

  // Q fragment (B-operand of S^T): B[n=q][k=d], q = qb0 + w*16 + n16
  bf16x8 aq[2];
  {
    const u16* qp = &qb[(bh * SS + qb0 + w * 16 + n16) * DHH];
    aq[0] = *(const bf16x8*)&qp[quad * 8];
    aq[1] = *(const bf16x8*)&qp[32 + quad * 8];
  }
  const int q_rel = w * 16 + n16;

  // staging: each thread moves 2x16B of K and 2x16B of V per tile
  const int c1 = 256 + t;
  const int row0 = t >> 3,  col0 = (t & 7) * 8;
  const int row1 = c1 >> 3, col1 = (c1 & 7) * 8;
  // key -> permuted LDS row: key = p*32 + quad*8 + b*4 + r  ->  (2p+b)*16 + quad*4 + r
  auto perm = [](int k) {
    int p = k >> 5, rem = k & 31, qd = rem >> 3, tt = rem & 7;
    return ((p << 1) | (tt >> 2)) * 16 + qd * 4 + (tt & 3);
  };
  const int prow0 = perm(row0), prow1 = perm(row1);

  float4 fk0, fk1, fv0, fv1;
  fk0 = *(const float4*)&kb[(bh * SS + row0) * DHH + col0];
  fk1 = *(const float4*)&kb[(bh * SS + row1) * DHH + col1];
  fv0 = *(const float4*)&vt[(bh * DHH + row0) * SS + col0];
  fv1 = *(const float4*)&vt[(bh * DHH + row1) * SS + col1];
  *(float4*)&Ks[0][prow0 * LDST + col0] = fk0;
  *(float4*)&Ks[0][prow1 * LDST + col1] = fk1;
  *(float4*)&Vs[0][row0 * LDST + col0] = fv0;
  *(float4*)&Vs[0][row1 * LDST + col1] = fv1;

  float m_i = -1e30f, l_i = 0.f;
  f32x4 o[4];
  for (int db = 0; db < 4; db++) o[db] = f32x4{0.f, 0.f, 0.f, 0.f};

  for (int kt = 0; kt <= qt; ++kt) {
    __syncthreads();
    const int cur = kt & 1, nxt = cur ^ 1;
    if (kt < qt) {   // prefetch next tile (latency hidden behind compute)
      int kk = (kt + 1) * 64;
      fk0 = *(const float4*)&kb[(bh * SS + kk + row0) * DHH + col0];
      fk1 = *(const float4*)&kb[(bh * SS + kk + row1) * DHH + col1];
      fv0 = *(const float4*)&vt[(bh * DHH + row0) * SS + kk + col0];
      fv1 = *(const float4*)&vt[(bh * DHH + row1) * SS + kk + col1];
    }

    // S^T = K * Q^T : A=K (m=permuted key), B=Q (n=q)
    f32x4 sc[4];
    for (int nb = 0; nb < 4; nb++) {
      f32x4 c = f32x4{0.f, 0.f, 0.f, 0.f};
      for (int ks = 0; ks < 2; ks++) {
        bf16x8 ak = *(const bf16x8*)&Ks[cur][(nb * 16 + n16) * LDST + ks * 32 + quad * 8];
        c = __builtin_amdgcn_mfma_f32_16x16x32_bf16(ak, aq[ks], c, 0, 0, 0);
      }
      sc[nb] = c;
    }
    // scale + causal mask; lane's key for (nb,r) = (nb>>1)*32 + quad*8 + (nb&1)*4 + r
    const bool diag = (kt == qt);
    for (int nb = 0; nb < 4; nb++)
      for (int r = 0; r < 4; r++) {
        float v = sc[nb][r] * 0.125f;
        int key = ((nb >> 1) << 5) + quad * 8 + ((nb & 1) << 2) + r;
        sc[nb][r] = (diag && key > q_rel) ? -1e30f : v;
      }

    // online softmax: per-lane q, stats replicated over the 4 quads
    float rm = -1e30f;
    for (int nb = 0; nb < 4; nb++)
      for (int r = 0; r < 4; r++) rm = fmaxf(rm, sc[nb][r]);
    rm = fmaxf(rm, __shfl_xor(rm, 16));
    rm = fmaxf(rm, __shfl_xor(rm, 32));
    float mnew = fmaxf(m_i, rm);
    float alpha = __expf(m_i - mnew);
    float p[4][4];
    float rs = 0.f;
    for (int nb = 0; nb < 4; nb++)
      for (int r = 0; r < 4; r++) { float pv = __expf(sc[nb][r] - mnew); p[nb][r] = pv; rs += pv; }
    rs += __shfl_xor(rs, 16);
    rs += __shfl_xor(rs, 32);
    l_i = l_i * alpha + rs;
    m_i = mnew;
    for (int db = 0; db < 4; db++)
      for (int r = 0; r < 4; r++) o[db][r] *= alpha;

    // O^T += V^T * P^T : A=V^T (m=d), B=P^T (n=q, k=key) -- P already in B layout
    for (int p2 = 0; p2 < 2; p2++) {
      union { bf16x8 v; u16 s[8]; } bp;
      for (int j = 0; j < 4; j++) {
        bp.s[j]     = f2bf(p[2 * p2][j]);
        bp.s[4 + j] = f2bf(p[2 * p2 + 1][j]);
      }
      for (int db = 0; db < 4; db++) {
        bf16x8 av = *(const bf16x8*)&Vs[cur][(db * 16 + n16) * LDST + p2 * 32 + quad * 8];
        o[db] = __builtin_amdgcn_mfma_f32_16x16x32_bf16(av, bp.v, o[db], 0, 0, 0);
      }
    }

    if (kt < qt) {   // write prefetched tile into the other buffer
      *(float4*)&Ks[nxt][prow0 * LDST + col0] = fk0;
      *(float4*)&Ks[nxt][prow1 * LDST + col1] = fk1;
      *(float4*)&Vs[nxt][row0 * LDST + col0] = fv0;
      *(float4*)&Vs[nxt][row1 * LDST + col1] = fv1;
    }
  }

  // epilogue: O^T[d][q] -> y[token][h*64+d]; lane owns q = q_rel, d = db*16+quad*4+r
  const float inv = 1.0f / l_i;
  const int tok = b_ * SS + qb0 + w * 16 + n16;
  for (int db = 0; db < 4; db++) {
    u16x4 pk = { f2bf(o[db][0] * inv), f2bf(o[db][1] * inv),
                 f2bf(o[db][2] * inv), f2bf(o[db][3] * inv) };
    *(u16x4*)&y[tok * EE + h * DHH + db * 16 + quad * 4] = pk;
  }
}

// ---------------------------------------------------------------- proj GEMM
// out[8192,640] fp32 = y[8192,640] * wproj[640,640]^T
__global__ __launch_bounds__(256) void gemm_proj(
    const u16* __restrict__ A, const u16* __restrict__ Bt, float* __restrict__ out) {
  __shared__ __align__(16) u16 As[128 * LDST];
  __shared__ __align__(16) u16 Bs[128 * LDST];
  const int t = threadIdx.x;
  const int m0 = blockIdx.y * 128;
  const int n0 = blockIdx.x * 128;
  const int w = t >> 6, lane = t & 63, n16 = lane & 15, quad = lane >> 4;
  const int wm = w >> 1, wn = w & 1;

  f32x4 acc[4][4];
  for (int i = 0; i < 4; i++)
    for (int j = 0; j < 4; j++) acc[i][j] = f32x4{0.f, 0.f, 0.f, 0.f};

  for (int kt = 0; kt < 10; ++kt) {
    __syncthreads();
    for (int i = 0; i < 4; ++i) {
      int c = i * 256 + t;
      int row = c >> 3, col0 = (c & 7) * 8;
      *(bf16x8*)&As[row * LDST + col0] = *(const bf16x8*)&A[(m0 + row) * 640 + kt * 64 + col0];
      *(bf16x8*)&Bs[row * LDST + col0] = *(const bf16x8*)&Bt[(n0 + row) * 640 + kt * 64 + col0];
    }
    __syncthreads();
    for (int ks = 0; ks < 2; ++ks) {
      bf16x8 a[4], b[4];
      for (int mi = 0; mi < 4; mi++)
        a[mi] = *(const bf16x8*)&As[(wm * 64 + mi * 16 + n16) * LDST + ks * 32 + quad * 8];
      for (int ni = 0; ni < 4; ni++)
        b[ni] = *(const bf16x8*)&Bs[(wn * 64 + ni * 16 + n16) * LDST + ks * 32 + quad * 8];
      for (int mi = 0; mi < 4; mi++)
        for (int ni = 0; ni < 4; ni++)
          acc[mi][ni] = __builtin_amdgcn_mfma_f32_16x16x32_bf16(a[mi], b[ni], acc[mi][ni], 0, 0, 0);
    }
  }

  for (int ni = 0; ni < 4; ni++) {
    int col = n0 + wn * 64 + ni * 16 + n16;
    for (int mi = 0; mi < 4; mi++) {
      int rowb = m0 + wm * 64 + mi * 16 + quad * 4;
      f32x4 c = acc[mi][ni];
      for (int r = 0; r < 4; r++) out[(rowb + r) * 640 + col] = c[r];
    }
  }
}

// ---------------------------------------------------------------- launch
extern "C" void kernel_launch(void* const* d_in, const int* in_sizes, int n_in,
                              void* d_out, int out_size, void* d_ws, size_t ws_size,
                              hipStream_t stream) {
  const float* x     = (const float*)d_in[0];   // [4,2048,640]
  const float* wqkv  = (const float*)d_in[1];   // [1920,640]
  const float* wproj = (const float*)d_in[2];   // [640,640]
  float* out = (float*)d_out;

  char* ws = (char*)d_ws;
  u16* xb     = (u16*)(ws + 0);            // 10,485,760 B
  u16* wqkvb  = (u16*)(ws + 10485760);     //  2,457,600 B
  u16* wprojb = (u16*)(ws + 12943360);     //    819,200 B
  u16* qbuf   = (u16*)(ws + 13762560);     // 10,485,760 B  [bh][s][d]
  u16* kbuf   = (u16*)(ws + 24248320);     // 10,485,760 B  [bh][s][d]
  u16* vtb    = (u16*)(ws + 34734080);     // 10,485,760 B  [bh][d][s]
  u16* ybuf   = (u16*)(ws + 45219840);     // 10,485,760 B  [tok][e]

  convert_kernel<<<5120, 256, 0, stream>>>(x, xb, 5242880 / 4);
  convert_kernel<<<1200, 256, 0, stream>>>(wqkv, wqkvb, 1228800 / 4);
  convert_kernel<<<400, 256, 0, stream>>>(wproj, wprojb, 409600 / 4);

  gemm_qkv<<<dim3(15, 64), 256, 0, stream>>>(xb, wqkvb, qbuf, kbuf, vtb);
  attn_kernel<<<dim3(40, 32), 256, 0, stream>>>(qbuf, kbuf, vtb, ybuf);
  gemm_proj<<<dim3(5, 64), 256, 0, stream>>>(ybuf, wprojb, out);
}